// Round 11
// baseline (304.625 us; speedup 1.0000x reference)
//
#include <hip/hip_runtime.h>

// Chamfer distance, B=16, N=M=4096, D=3.
// dist(i,j) = n1 + n2 - 2*x1.x2 as ONE bf16 MFMA per 32x32 tile (norms folded
// into padded K slots, hi/lo bf16 split => exact-grade; absmax 0.0 since R1).
// R15: occupancy 4 -> 8 waves/SIMD. R14 (84.1 us, best) holds 2 blocks/CU
// (64 KB LDS each) = 4 waves/SIMD; R11 probes showed MfmaUtil 37/VALU 50 —
// dependency-stall-bound, neither pipe saturated. VGPR=52 measured => HW
// allows 8 waves/SIMD if LDS <= 32 KB/block. So: col-QUARTER panels (32
// tiles, 32 KB), grid.x 64->128, launch_bounds(512,8) (VGPR cap 64 > 52).
// 4 blocks/CU x 8 waves = 32 waves/CU. Same total MFMA work; prologue cheap
// (fused panel build, 2 pts/thread). Spill check: WRITE_SIZE fingerprint.
//  - MFMA floor: 524288 MFMAs / 1024 SIMDs x 32cyc = 6.8 us.
//  - inner loop / epilogue / reduce unchanged from R14.

typedef __attribute__((ext_vector_type(8))) __bf16 bf16x8;
typedef __attribute__((ext_vector_type(16))) float f32x16;

#define PTS 4096
#define NB 16

__device__ __forceinline__ unsigned f2bf(float f) {
  unsigned u = __float_as_uint(f);
  return (u + 0x7FFFu + ((u >> 16) & 1u)) >> 16;  // RNE bf16 bits
}
__device__ __forceinline__ float bf2f(unsigned s) {
  return __uint_as_float(s << 16);
}
__device__ __forceinline__ unsigned pk(unsigned lo, unsigned hi) {
  return (lo & 0xFFFFu) | (hi << 16);
}

// ---- main: 512 threads (8 waves). Block builds its 32-tile (1024-col)
// B-panel in LDS from raw points, then all 8 waves stream it (2 row-tiles
// per wave = 512 rows/block). grid.x = 128 slices (dir,b,cq) -> XCD = x%8 ;
// grid.y = 8 row-groups. 1024 blocks = 4/CU = 8 waves/SIMD.
__global__ __launch_bounds__(512, 8) void chamfer_main(
    const float* __restrict__ x1, const float* __restrict__ x2,
    unsigned* __restrict__ rowm) {
  const int s  = blockIdx.x;           // 128 slices: (dir, batch, col-quarter)
  const int d  = s & 1;
  const int b  = (s >> 1) & (NB - 1);
  const int cq = (s >> 5) & 3;
  const int rg = blockIdx.y;           // 8 row-groups of 512 rows

  const int tid  = threadIdx.x;
  const int lane = tid & 63;
  const int half = lane >> 5;          // K-half this lane supplies to MFMA
  const int l31  = lane & 31;
  const int wave = tid >> 6;           // 0..7

  __shared__ uint4 lds[2048];          // 32 tiles x 1 KB = 32 KB

  // --- build B-panel in LDS from raw col-side points ---
  // B k-vec: w0=[Hx Hy Hz Lx Ly Lz Hx Hy] w1=[Hz nh nl 1 1 0 0 0], H,L = -2q.
  const float* Q = d ? x1 : x2;        // col side = opposite of row side
  const int cbase = b * PTS + cq * 1024;
#pragma unroll
  for (int k = 0; k < 2; ++k) {
    const int j = tid + k * 512;       // 1024 panel points
    const float* q = Q + (size_t)(cbase + j) * 3;
    const float x = q[0], y = q[1], z = q[2];
    const float sx = -2.f * x, sy = -2.f * y, sz = -2.f * z;
    const unsigned Hx = f2bf(sx), Hy = f2bf(sy), Hz = f2bf(sz);
    const unsigned Lx = f2bf(sx - bf2f(Hx));
    const unsigned Ly = f2bf(sy - bf2f(Hy));
    const unsigned Lz = f2bf(sz - bf2f(Hz));
    const float n = fmaf(x, x, fmaf(y, y, z * z));
    const unsigned nh = f2bf(n), nl = f2bf(n - bf2f(nh));
    const unsigned one = 0x3F80u;
    uint4 w0, w1;
    w0.x = pk(Hx, Hy); w0.y = pk(Hz, Lx); w0.z = pk(Ly, Lz); w0.w = pk(Hx, Hy);
    w1.x = pk(Hz, nh); w1.y = pk(nl, one); w1.z = pk(one, 0u); w1.w = 0u;
    lds[(j >> 5) * 64 + (j & 31)]      = w0;  // half 0 (k 0..7)
    lds[(j >> 5) * 64 + 32 + (j & 31)] = w1;  // half 1 (k 8..15)
  }

  // --- build A fragments from raw points (row tiles t0, t0+1) ---
  // A k-vec: w0=[hx hy hz hx hy hz lx ly]  w1=[lz 1 1 nh nl 0 0 0]
  const float* P = d ? x2 : x1;
  const int t0 = rg * 16 + wave * 2;
  bf16x8 af[2];
#pragma unroll
  for (int rr = 0; rr < 2; ++rr) {
    const int r = (t0 + rr) * 32 + l31;
    const float* p = P + (size_t)(b * PTS + r) * 3;
    const float x = p[0], y = p[1], zc = p[2];
    const unsigned hx = f2bf(x), hy = f2bf(y), hz = f2bf(zc);
    const unsigned lx = f2bf(x - bf2f(hx));
    const unsigned ly = f2bf(y - bf2f(hy));
    const unsigned lz = f2bf(zc - bf2f(hz));
    const float n = fmaf(x, x, fmaf(y, y, zc * zc));
    const unsigned nh = f2bf(n), nl = f2bf(n - bf2f(nh));
    const unsigned one = 0x3F80u;
    uint4 w0, w1;
    w0.x = pk(hx, hy); w0.y = pk(hz, hx); w0.z = pk(hy, hz); w0.w = pk(lx, ly);
    w1.x = pk(lz, one); w1.y = pk(one, nh); w1.z = pk(nl, 0u); w1.w = 0u;
    uint4 w;
    w.x = half ? w1.x : w0.x; w.y = half ? w1.y : w0.y;
    w.z = half ? w1.z : w0.z; w.w = half ? w1.w : w0.w;
    af[rr] = *(const bf16x8*)&w;
  }
  const bf16x8 af0 = af[0], af1 = af[1];

  f32x16 zero;
#pragma unroll
  for (int e = 0; e < 16; ++e) zero[e] = 0.f;

  float rm0[16], rm1[16];
#pragma unroll
  for (int e = 0; e < 16; ++e) { rm0[e] = 3.0e38f; rm1[e] = 3.0e38f; }

  __syncthreads();  // panel staged (read-only afterwards: no more barriers)

  // --- stream 32 tiles from LDS; 4-slot ring, 2 reads in flight ---
  const uint4* tp = &lds[half * 32 + l31];  // tile stride = 64 uint4
  bf16x8 buf[4];
  buf[0] = *(const bf16x8*)&tp[0];
  buf[1] = *(const bf16x8*)&tp[64];

#pragma unroll 2
  for (int g = 0; g < 16; ++g) {
    const int cur = (g & 1) * 2;
    const int nxt = ((g + 1) & 1) * 2;
    const int pf  = ((g + 1) & 15) * 2;  // wrap: last prefetch redundant, safe
    buf[nxt]     = *(const bf16x8*)&tp[pf * 64];
    buf[nxt + 1] = *(const bf16x8*)&tp[(pf + 1) * 64];
    const bf16x8 b0 = buf[cur], b1 = buf[cur + 1];
    const f32x16 a00 =
        __builtin_amdgcn_mfma_f32_32x32x16_bf16(af0, b0, zero, 0, 0, 0);
    const f32x16 a01 =
        __builtin_amdgcn_mfma_f32_32x32x16_bf16(af0, b1, zero, 0, 0, 0);
#pragma unroll
    for (int e = 0; e < 16; ++e)
      rm0[e] = fminf(fminf(a00[e], a01[e]), rm0[e]);  // v_min3_f32
    const f32x16 a10 =
        __builtin_amdgcn_mfma_f32_32x32x16_bf16(af1, b0, zero, 0, 0, 0);
    const f32x16 a11 =
        __builtin_amdgcn_mfma_f32_32x32x16_bf16(af1, b1, zero, 0, 0, 0);
#pragma unroll
    for (int e = 0; e < 16; ++e)
      rm1[e] = fminf(fminf(a10[e], a11[e]), rm1[e]);
  }

  // --- per-row min over this wave's 32 cols-per-half, then uint atomicMin ---
  // C/D layout: col = lane&31, row_local = (e&3) + 8*(e>>2) + 4*half.
  unsigned* rbase = rowm + (size_t)(d * NB + b) * PTS + t0 * 32;
#pragma unroll
  for (int e = 0; e < 16; ++e) {
    float v = rm0[e];
    v = fminf(v, __shfl_xor(v, 1));
    v = fminf(v, __shfl_xor(v, 2));
    v = fminf(v, __shfl_xor(v, 4));
    v = fminf(v, __shfl_xor(v, 8));
    v = fminf(v, __shfl_xor(v, 16));
    if (l31 == e) {
      const int rl = (e & 3) + 8 * (e >> 2) + 4 * half;
      atomicMin(rbase + rl, __float_as_uint(fmaxf(v, 0.f)));
    }
  }
#pragma unroll
  for (int e = 0; e < 16; ++e) {
    float v = rm1[e];
    v = fminf(v, __shfl_xor(v, 1));
    v = fminf(v, __shfl_xor(v, 2));
    v = fminf(v, __shfl_xor(v, 4));
    v = fminf(v, __shfl_xor(v, 8));
    v = fminf(v, __shfl_xor(v, 16));
    if (l31 == e) {
      const int rl = 32 + (e & 3) + 8 * (e >> 2) + 4 * half;
      atomicMin(rbase + rl, __float_as_uint(fmaxf(v, 0.f)));
    }
  }
}

// ---- reduce: out[b] += partial sums of rowmin; 64 blocks (b, quarter) ----
__global__ __launch_bounds__(256) void reduce_rows(
    const unsigned* __restrict__ rowm, float* __restrict__ out) {
  const int b = blockIdx.x >> 2;
  const int seg = blockIdx.x & 3;
  const int tid = threadIdx.x;
  const unsigned* r0 = rowm + (size_t)b * PTS + seg * 1024;
  const unsigned* r1 = rowm + (size_t)(NB + b) * PTS + seg * 1024;
  float s = 0.f;
  for (int i = tid; i < 1024; i += 256)
    s += __uint_as_float(r0[i]) + __uint_as_float(r1[i]);
  s += __shfl_xor(s, 1);
  s += __shfl_xor(s, 2);
  s += __shfl_xor(s, 4);
  s += __shfl_xor(s, 8);
  s += __shfl_xor(s, 16);
  s += __shfl_xor(s, 32);
  __shared__ float acc[4];
  if ((tid & 63) == 0) acc[tid >> 6] = s;
  __syncthreads();
  if (tid == 0)
    atomicAdd(&out[b], (acc[0] + acc[1] + acc[2] + acc[3]) * (1.f / PTS));
}

extern "C" void kernel_launch(void* const* d_in, const int* in_sizes, int n_in,
                              void* d_out, int out_size, void* d_ws,
                              size_t ws_size, hipStream_t stream) {
  const float* x1 = (const float*)d_in[0];
  const float* x2 = (const float*)d_in[1];
  float* out = (float*)d_out;

  unsigned* rowm = (unsigned*)d_ws;  // 2*NB*PTS uint = 512 KB

  // 0x7F7F7F7F as float = 3.39e38 > any squared distance here: valid
  // atomicMin identity (positive-float bit order is monotone).
  hipMemsetAsync(rowm, 0x7F, (size_t)2 * NB * PTS * 4, stream);
  hipMemsetAsync(out, 0, NB * sizeof(float), stream);

  dim3 grid(128, 8);  // x = (dir,b,cq) slice -> XCD = x%8 ; y = row-group
  chamfer_main<<<grid, 512, 0, stream>>>(x1, x2, rowm);
  reduce_rows<<<64, 256, 0, stream>>>(rowm, out);
}

// Round 12
// 81.225 us; speedup vs baseline: 3.7504x; 3.7504x over previous
//
#include <hip/hip_runtime.h>

// Chamfer distance, B=16, N=M=4096, D=3.
// dist(i,j) = n1 + n2 - 2*x1.x2 as ONE bf16 MFMA per 32x32 tile (norms folded
// into padded K slots, hi/lo bf16 split => exact-grade; absmax 0.0 since R1).
// R16: overhead shave. R15 settled occupancy: true per-wave footprint ~130
// regs (52 arch-VGPR + ~80 unified-AGPR accumulators) => 4 waves/SIMD max;
// R14's 2 blocks/CU x 8 waves already achieves it (R12/R15 proved both
// directions). Main loop kept byte-identical to R14 (best, 84.1 us). Changes:
//  - NO memsets: epilogue does direct stores into rowpart[(ch*2+d)*NB+b][row]
//    (each row written exactly once per col-half -> no init, no atomicMin)
//  - reduce: 16 blocks x 512, min over halves + clamp + sum, direct out[b]
//  - dispatches 4 -> 2 (after harness fill): fewer launch gaps
// Budget: 41 us fill (fixed) + ~28 us main (latency-bound at max residency)
// + reduce/gaps. Predicted 84 -> ~76-80 us.

typedef __attribute__((ext_vector_type(8))) __bf16 bf16x8;
typedef __attribute__((ext_vector_type(16))) float f32x16;

#define PTS 4096
#define NB 16

__device__ __forceinline__ unsigned f2bf(float f) {
  unsigned u = __float_as_uint(f);
  return (u + 0x7FFFu + ((u >> 16) & 1u)) >> 16;  // RNE bf16 bits
}
__device__ __forceinline__ float bf2f(unsigned s) {
  return __uint_as_float(s << 16);
}
__device__ __forceinline__ unsigned pk(unsigned lo, unsigned hi) {
  return (lo & 0xFFFFu) | (hi << 16);
}

// ---- main: 512 threads (8 waves). Block builds its 64-tile (2048-col)
// B-panel in LDS from raw points, then all 8 waves stream it (2 row-tiles
// per wave = 512 rows/block). grid.x = 64 slices (dir,b,ch) -> XCD = x%8 ;
// grid.y = 8 row-groups. 512 blocks = 2/CU (64KB LDS), 4 waves/SIMD (reg cap).
__global__ __launch_bounds__(512, 2) void chamfer_main(
    const float* __restrict__ x1, const float* __restrict__ x2,
    float* __restrict__ rowpart) {
  const int s  = blockIdx.x;           // 64 slices: (dir, batch, colhalf)
  const int d  = s & 1;
  const int b  = (s >> 1) & (NB - 1);
  const int ch = (s >> 5) & 1;
  const int rg = blockIdx.y;           // 8 row-groups of 512 rows

  const int tid  = threadIdx.x;
  const int lane = tid & 63;
  const int half = lane >> 5;          // K-half this lane supplies to MFMA
  const int l31  = lane & 31;
  const int wave = tid >> 6;           // 0..7

  __shared__ uint4 lds[4096];          // 64 tiles x 1 KB = 64 KB

  // --- build B-panel in LDS from raw col-side points ---
  // B k-vec: w0=[Hx Hy Hz Lx Ly Lz Hx Hy] w1=[Hz nh nl 1 1 0 0 0], H,L = -2q.
  const float* Q = d ? x1 : x2;        // col side = opposite of row side
  const int cbase = b * PTS + ch * 2048;
#pragma unroll
  for (int k = 0; k < 4; ++k) {
    const int j = tid + k * 512;       // 2048 panel points
    const float* q = Q + (size_t)(cbase + j) * 3;
    const float x = q[0], y = q[1], z = q[2];
    const float sx = -2.f * x, sy = -2.f * y, sz = -2.f * z;
    const unsigned Hx = f2bf(sx), Hy = f2bf(sy), Hz = f2bf(sz);
    const unsigned Lx = f2bf(sx - bf2f(Hx));
    const unsigned Ly = f2bf(sy - bf2f(Hy));
    const unsigned Lz = f2bf(sz - bf2f(Hz));
    const float n = fmaf(x, x, fmaf(y, y, z * z));
    const unsigned nh = f2bf(n), nl = f2bf(n - bf2f(nh));
    const unsigned one = 0x3F80u;
    uint4 w0, w1;
    w0.x = pk(Hx, Hy); w0.y = pk(Hz, Lx); w0.z = pk(Ly, Lz); w0.w = pk(Hx, Hy);
    w1.x = pk(Hz, nh); w1.y = pk(nl, one); w1.z = pk(one, 0u); w1.w = 0u;
    lds[(j >> 5) * 64 + (j & 31)]      = w0;  // half 0 (k 0..7)
    lds[(j >> 5) * 64 + 32 + (j & 31)] = w1;  // half 1 (k 8..15)
  }

  // --- build A fragments from raw points (row tiles t0, t0+1) ---
  // A k-vec: w0=[hx hy hz hx hy hz lx ly]  w1=[lz 1 1 nh nl 0 0 0]
  const float* P = d ? x2 : x1;
  const int t0 = rg * 16 + wave * 2;
  bf16x8 af[2];
#pragma unroll
  for (int rr = 0; rr < 2; ++rr) {
    const int r = (t0 + rr) * 32 + l31;
    const float* p = P + (size_t)(b * PTS + r) * 3;
    const float x = p[0], y = p[1], zc = p[2];
    const unsigned hx = f2bf(x), hy = f2bf(y), hz = f2bf(zc);
    const unsigned lx = f2bf(x - bf2f(hx));
    const unsigned ly = f2bf(y - bf2f(hy));
    const unsigned lz = f2bf(zc - bf2f(hz));
    const float n = fmaf(x, x, fmaf(y, y, zc * zc));
    const unsigned nh = f2bf(n), nl = f2bf(n - bf2f(nh));
    const unsigned one = 0x3F80u;
    uint4 w0, w1;
    w0.x = pk(hx, hy); w0.y = pk(hz, hx); w0.z = pk(hy, hz); w0.w = pk(lx, ly);
    w1.x = pk(lz, one); w1.y = pk(one, nh); w1.z = pk(nl, 0u); w1.w = 0u;
    uint4 w;
    w.x = half ? w1.x : w0.x; w.y = half ? w1.y : w0.y;
    w.z = half ? w1.z : w0.z; w.w = half ? w1.w : w0.w;
    af[rr] = *(const bf16x8*)&w;
  }
  const bf16x8 af0 = af[0], af1 = af[1];

  f32x16 zero;
#pragma unroll
  for (int e = 0; e < 16; ++e) zero[e] = 0.f;

  float rm0[16], rm1[16];
#pragma unroll
  for (int e = 0; e < 16; ++e) { rm0[e] = 3.0e38f; rm1[e] = 3.0e38f; }

  __syncthreads();  // panel staged (read-only afterwards: no more barriers)

  // --- stream 64 tiles from LDS; 4-slot ring, 2 reads in flight ---
  const uint4* tp = &lds[half * 32 + l31];  // tile stride = 64 uint4
  bf16x8 buf[4];
  buf[0] = *(const bf16x8*)&tp[0];
  buf[1] = *(const bf16x8*)&tp[64];

#pragma unroll 2
  for (int g = 0; g < 32; ++g) {
    const int cur = (g & 1) * 2;
    const int nxt = ((g + 1) & 1) * 2;
    const int pf  = ((g + 1) & 31) * 2;  // wrap: last prefetch redundant, safe
    buf[nxt]     = *(const bf16x8*)&tp[pf * 64];
    buf[nxt + 1] = *(const bf16x8*)&tp[(pf + 1) * 64];
    const bf16x8 b0 = buf[cur], b1 = buf[cur + 1];
    const f32x16 a00 =
        __builtin_amdgcn_mfma_f32_32x32x16_bf16(af0, b0, zero, 0, 0, 0);
    const f32x16 a01 =
        __builtin_amdgcn_mfma_f32_32x32x16_bf16(af0, b1, zero, 0, 0, 0);
#pragma unroll
    for (int e = 0; e < 16; ++e)
      rm0[e] = fminf(fminf(a00[e], a01[e]), rm0[e]);  // v_min3_f32
    const f32x16 a10 =
        __builtin_amdgcn_mfma_f32_32x32x16_bf16(af1, b0, zero, 0, 0, 0);
    const f32x16 a11 =
        __builtin_amdgcn_mfma_f32_32x32x16_bf16(af1, b1, zero, 0, 0, 0);
#pragma unroll
    for (int e = 0; e < 16; ++e)
      rm1[e] = fminf(fminf(a10[e], a11[e]), rm1[e]);
  }

  // --- per-row min over this wave's 32 cols-per-half, direct store ---
  // C/D layout: col = lane&31, row_local = (e&3) + 8*(e>>2) + 4*half.
  // Each row written exactly once per col-half: no init, no atomics.
  float* rbase = rowpart + ((size_t)((ch * 2 + d) * NB + b)) * PTS + t0 * 32;
#pragma unroll
  for (int e = 0; e < 16; ++e) {
    float v = rm0[e];
    v = fminf(v, __shfl_xor(v, 1));
    v = fminf(v, __shfl_xor(v, 2));
    v = fminf(v, __shfl_xor(v, 4));
    v = fminf(v, __shfl_xor(v, 8));
    v = fminf(v, __shfl_xor(v, 16));
    if (l31 == e) {
      const int rl = (e & 3) + 8 * (e >> 2) + 4 * half;
      rbase[rl] = fmaxf(v, 0.f);
    }
  }
#pragma unroll
  for (int e = 0; e < 16; ++e) {
    float v = rm1[e];
    v = fminf(v, __shfl_xor(v, 1));
    v = fminf(v, __shfl_xor(v, 2));
    v = fminf(v, __shfl_xor(v, 4));
    v = fminf(v, __shfl_xor(v, 8));
    v = fminf(v, __shfl_xor(v, 16));
    if (l31 == e) {
      const int rl = 32 + (e & 3) + 8 * (e >> 2) + 4 * half;
      rbase[rl] = fmaxf(v, 0.f);
    }
  }
}

// ---- reduce: out[b] = mean_r min(ch0,ch1)[d=0] + mean_r min(ch0,ch1)[d=1] ----
// Planes: p = ch*2 + d -> d=0 in planes {0,2}, d=1 in planes {1,3}.
__global__ __launch_bounds__(512) void reduce_rows(
    const float* __restrict__ rowpart, float* __restrict__ out) {
  const int b = blockIdx.x;
  const int tid = threadIdx.x;
  const float* p0 = rowpart + (size_t)(0 * NB + b) * PTS;  // ch0,d0
  const float* p1 = rowpart + (size_t)(1 * NB + b) * PTS;  // ch0,d1
  const float* p2 = rowpart + (size_t)(2 * NB + b) * PTS;  // ch1,d0
  const float* p3 = rowpart + (size_t)(3 * NB + b) * PTS;  // ch1,d1
  float s = 0.f;
  for (int i = tid; i < PTS; i += 512)
    s += fminf(p0[i], p2[i]) + fminf(p1[i], p3[i]);
  s += __shfl_xor(s, 1);
  s += __shfl_xor(s, 2);
  s += __shfl_xor(s, 4);
  s += __shfl_xor(s, 8);
  s += __shfl_xor(s, 16);
  s += __shfl_xor(s, 32);
  __shared__ float acc[8];
  if ((tid & 63) == 0) acc[tid >> 6] = s;
  __syncthreads();
  if (tid == 0) {
    float t = 0.f;
#pragma unroll
    for (int w = 0; w < 8; ++w) t += acc[w];
    out[b] = t * (1.f / PTS);
  }
}

extern "C" void kernel_launch(void* const* d_in, const int* in_sizes, int n_in,
                              void* d_out, int out_size, void* d_ws,
                              size_t ws_size, hipStream_t stream) {
  const float* x1 = (const float*)d_in[0];
  const float* x2 = (const float*)d_in[1];
  float* out = (float*)d_out;

  float* rowpart = (float*)d_ws;  // 4*NB*PTS floats = 1 MB, fully overwritten

  dim3 grid(64, 8);  // x = (dir,b,ch) slice -> XCD = x%8 ; y = row-group
  chamfer_main<<<grid, 512, 0, stream>>>(x1, x2, rowpart);
  reduce_rows<<<NB, 512, 0, stream>>>(rowpart, out);
}